// Round 5
// baseline (140.676 us; speedup 1.0000x reference)
//
#include <hip/hip_runtime.h>

#define EPS_BN 1e-5f
#define FDIM 512        // face feature dim
#define F4   128        // FDIM/4
#define HDIM 32
#define NB_XS 64        // partial-sum blocks for xsums
#define NBH   64        // histogram blocks
#define MAXBKT 1024     // max dst buckets (n <= 65536)

// ---------------------------------------------------------------------------
__device__ __forceinline__ int dot4i8(unsigned a, unsigned b) {
#if __has_builtin(__builtin_amdgcn_sdot4)
    return __builtin_amdgcn_sdot4((int)a, (int)b, 0, false);
#else
    int s;
    s  = (int)(signed char)(a      ) * (int)(signed char)(b      );
    s += (int)(signed char)(a >>  8) * (int)(signed char)(b >>  8);
    s += (int)(signed char)(a >> 16) * (int)(signed char)(b >> 16);
    s += (int)(signed char)(a >> 24) * (int)(signed char)(b >> 24);
    return s;
#endif
}

__device__ __forceinline__ float atomicReadF(float* p) { return atomicAdd(p, 0.0f); }
__device__ __forceinline__ int   atomicReadI(int* p)   { return atomicAdd(p, 0); }

// ---------------------------------------------------------------------------
// K_A (k_prep): three block families in one launch:
//   [0,qb)            : per-row normalize + int8 quantize (+zero deg)
//   [qb,qb+NB_XS)     : 5-scalar partial sums over x -> atomic xs;
//                       LAST such block computes fused params (ticket)
//   [qb+NB_XS, +NBH)  : dst-bucket histogram -> atomic hist;
//                       LAST such block does exclusive prefix -> bucket_ptr
// ---------------------------------------------------------------------------
__global__ __launch_bounds__(256)
void k_prep(const float* __restrict__ face,
            const float* __restrict__ x,
            const int* __restrict__ dst,
            uint2* __restrict__ qrows,
            float* __restrict__ scales,
            float* __restrict__ deg,
            float* __restrict__ xs,        // [5] zeroed
            int*   __restrict__ tick,      // [2] zeroed
            int*   __restrict__ hist,      // [MAXBKT] zeroed
            int*   __restrict__ bucket_ptr,// [MAXBKT]
            const float* __restrict__ W1, const float* __restrict__ b1,
            const float* __restrict__ gamma, const float* __restrict__ beta,
            const float* __restrict__ Wg, const float* __restrict__ bg,
            const float* __restrict__ wf, const float* __restrict__ b0,
            const float* __restrict__ bf,
            float* __restrict__ params,
            int n, int ne, int qb, int nbkt) {
    int tid = threadIdx.x;

    if ((int)blockIdx.x < qb) {
        // ---- quant: one wave per row ----
        int row  = (int)((blockIdx.x * 256 + tid) >> 6);
        int lane = tid & 63;
        if (row >= n) return;
        const float4* f4 = (const float4*)face + (size_t)row * F4;
        float4 a = f4[lane];
        float4 b = f4[lane + 64];
        float ss = a.x*a.x + a.y*a.y + a.z*a.z + a.w*a.w
                 + b.x*b.x + b.y*b.y + b.z*b.z + b.w*b.w;
        float mx = fmaxf(fmaxf(fmaxf(fabsf(a.x), fabsf(a.y)),
                               fmaxf(fabsf(a.z), fabsf(a.w))),
                         fmaxf(fmaxf(fabsf(b.x), fabsf(b.y)),
                               fmaxf(fabsf(b.z), fabsf(b.w))));
        #pragma unroll
        for (int off = 32; off > 0; off >>= 1) {
            ss += __shfl_xor(ss, off);
            mx  = fmaxf(mx, __shfl_xor(mx, off));
        }
        float rn = rsqrtf(ss + 1e-12f);
        float qs = (mx > 0.f) ? 127.0f / mx : 0.f;
        unsigned da =  ((unsigned)(__float2int_rn(a.x*qs) & 255))
                    | (((unsigned)(__float2int_rn(a.y*qs) & 255)) << 8)
                    | (((unsigned)(__float2int_rn(a.z*qs) & 255)) << 16)
                    | (((unsigned)(__float2int_rn(a.w*qs) & 255)) << 24);
        unsigned db =  ((unsigned)(__float2int_rn(b.x*qs) & 255))
                    | (((unsigned)(__float2int_rn(b.y*qs) & 255)) << 8)
                    | (((unsigned)(__float2int_rn(b.z*qs) & 255)) << 16)
                    | (((unsigned)(__float2int_rn(b.w*qs) & 255)) << 24);
        qrows[(size_t)row * 64 + lane] = make_uint2(da, db);
        if (lane == 0) {
            scales[row] = mx * rn * (1.0f / 127.0f);
            deg[row]    = 0.f;
        }
        return;
    }

    if ((int)blockIdx.x < qb + NB_XS) {
        // ---- xsums + params ticket ----
        __shared__ float red[4][5];
        __shared__ int amlast;
        int bid = (int)blockIdx.x - qb;
        float s0=0.f, s1=0.f, s00=0.f, s01=0.f, s11=0.f;
        for (int i = bid * 256 + tid; i < n; i += NB_XS * 256) {
            float2 xv = ((const float2*)x)[i];
            s0  += xv.x;       s1  += xv.y;
            s00 += xv.x*xv.x;  s01 += xv.x*xv.y;  s11 += xv.y*xv.y;
        }
        #pragma unroll
        for (int off = 32; off > 0; off >>= 1) {
            s0  += __shfl_xor(s0,  off);
            s1  += __shfl_xor(s1,  off);
            s00 += __shfl_xor(s00, off);
            s01 += __shfl_xor(s01, off);
            s11 += __shfl_xor(s11, off);
        }
        int lane = tid & 63, w = tid >> 6;
        if (lane == 0) {
            red[w][0]=s0; red[w][1]=s1; red[w][2]=s00; red[w][3]=s01; red[w][4]=s11;
        }
        __syncthreads();
        if (tid < 5) {
            atomicAdd(&xs[tid], red[0][tid] + red[1][tid] + red[2][tid] + red[3][tid]);
        }
        if (tid == 0) {
            __threadfence();
            amlast = (atomicAdd(&tick[0], 1) == NB_XS - 1);
        }
        __syncthreads();
        if (!amlast) return;
        // last xsums block: compute fused params
        __shared__ float xsl[5];
        if (tid < 5) xsl[tid] = atomicReadF(&xs[tid]);
        __syncthreads();
        float invN = 1.0f / (float)n;
        float m0 = xsl[0]*invN, m1 = xsl[1]*invN;
        float c00 = xsl[2]*invN - m0*m0;
        float c01 = xsl[3]*invN - m0*m1;
        float c11 = xsl[4]*invN - m1*m1;
        if (tid < HDIM) {
            float w0j = W1[tid], w1j = W1[HDIM + tid];
            float mu  = m0*w0j + m1*w1j + b1[tid];
            float var = c00*w0j*w0j + 2.f*c01*w0j*w1j + c11*w1j*w1j;
            float aa  = gamma[tid] * rsqrtf(var + EPS_BN);
            params[tid]        = aa;
            params[HDIM + tid] = beta[tid] - mu*aa;
            float v = 0.f;
            for (int m = 0; m < HDIM; ++m) v += Wg[tid*HDIM + m] * wf[m];
            params[2*HDIM + tid] = v;
        } else if (tid == HDIM) {
            float c = b0[0] + bf[0];
            for (int m = 0; m < HDIM; ++m) c += bg[m] * wf[m];
            params[3*HDIM] = c;
        }
        return;
    }

    // ---- histogram + prefix ticket ----
    {
        __shared__ int amlast;
        int bid = (int)blockIdx.x - qb - NB_XS;
        for (int e = bid * 256 + tid; e < ne; e += NBH * 256)
            atomicAdd(&hist[dst[e] >> 6], 1);
        if (tid == 0) {
            __threadfence();
            amlast = (atomicAdd(&tick[1], 1) == NBH - 1);
        }
        __syncthreads();
        if (!amlast) return;
        // last hist block: exclusive prefix over nbkt (<= MAXBKT) buckets
        __shared__ int sh[MAXBKT];
        __shared__ int tsum[256];
        for (int k = tid; k < MAXBKT; k += 256)
            sh[k] = (k < nbkt) ? atomicReadI(&hist[k]) : 0;
        __syncthreads();
        int k0 = tid * 4;
        int a0 = sh[k0], a1 = sh[k0+1], a2 = sh[k0+2], a3 = sh[k0+3];
        int p0 = a0, p1 = p0 + a1, p2 = p1 + a2, p3 = p2 + a3;
        tsum[tid] = p3;
        __syncthreads();
        for (int off = 1; off < 256; off <<= 1) {
            int v = (tid >= off) ? tsum[tid - off] : 0;
            __syncthreads();
            tsum[tid] += v;
            __syncthreads();
        }
        int base = (tid > 0) ? tsum[tid - 1] : 0;
        if (k0     < MAXBKT) bucket_ptr[k0]     = base;
        if (k0 + 1 < MAXBKT) bucket_ptr[k0 + 1] = base + p0;
        if (k0 + 2 < MAXBKT) bucket_ptr[k0 + 2] = base + p1;
        if (k0 + 3 < MAXBKT) bucket_ptr[k0 + 3] = base + p2;
    }
}

// ---------------------------------------------------------------------------
// K_B (k_mid): [0,nbn): node encoder; [nbn,..): counting-sort scatter
// ---------------------------------------------------------------------------
__global__ __launch_bounds__(256)
void k_mid(const float* __restrict__ x,
           const float* __restrict__ W1, const float* __restrict__ b1,
           const float* __restrict__ alpha,
           const float* __restrict__ W2, const float* __restrict__ b2,
           const float* __restrict__ w0,
           const float* __restrict__ params,
           const int* __restrict__ src, const int* __restrict__ dst,
           int* __restrict__ bucket_ptr,
           int* __restrict__ se_src, int* __restrict__ se_dst,
           float* __restrict__ sarr, float* __restrict__ out,
           int n, int ne, int nbn) {
    if ((int)blockIdx.x < nbn) {
        __shared__ float sW2[HDIM*HDIM];
        __shared__ float sW1[2*HDIM], sb1[HDIM], sa[HDIM], sbsh[HDIM];
        __shared__ float sv[HDIM], sw0[HDIM], sb2[HDIM];
        __shared__ float sc, salpha;
        for (int i = threadIdx.x; i < HDIM*HDIM; i += blockDim.x) sW2[i] = W2[i];
        if (threadIdx.x < 2*HDIM) sW1[threadIdx.x] = W1[threadIdx.x];
        if (threadIdx.x < HDIM) {
            sb1[threadIdx.x]  = b1[threadIdx.x];
            sa[threadIdx.x]   = params[threadIdx.x];
            sbsh[threadIdx.x] = params[HDIM + threadIdx.x];
            sv[threadIdx.x]   = params[2*HDIM + threadIdx.x];
            sw0[threadIdx.x]  = w0[threadIdx.x];
            sb2[threadIdx.x]  = b2[threadIdx.x];
        }
        if (threadIdx.x == 0) { sc = params[3*HDIM]; salpha = alpha[0]; }
        __syncthreads();
        int i = blockIdx.x * blockDim.x + threadIdx.x;
        if (i >= n) return;
        float2 xv = ((const float2*)x)[i];
        float h[HDIM];
        #pragma unroll
        for (int j = 0; j < HDIM; ++j) {
            float t = xv.x*sW1[j] + xv.y*sW1[HDIM + j] + sb1[j];
            t = sa[j]*t + sbsh[j];
            h[j] = (t >= 0.f) ? t : salpha*t;
        }
        float em[HDIM];
        #pragma unroll
        for (int k = 0; k < HDIM; ++k) em[k] = sb2[k];
        #pragma unroll
        for (int j = 0; j < HDIM; ++j) {
            float hj = h[j];
            #pragma unroll
            for (int k = 0; k < HDIM; ++k) em[k] += hj * sW2[j*HDIM + k];
        }
        float sdot = 0.f, ldot = 0.f;
        #pragma unroll
        for (int k = 0; k < HDIM; ++k) { sdot += em[k]*sv[k]; ldot += em[k]*sw0[k]; }
        sarr[i] = sdot;
        out[i]  = ldot + sc;    // base; GCN terms added in k_finish
    } else {
        int e = ((int)blockIdx.x - nbn) * 256 + threadIdx.x;
        if (e >= ne) return;
        int d = dst[e];
        int pos = atomicAdd(&bucket_ptr[d >> 6], 1);
        se_src[pos] = src[e];
        se_dst[pos] = d;
    }
}

// ---------------------------------------------------------------------------
// K_C (k_edge): sorted edge dots. 8 lanes/edge, 32 edges/block.
// XCD-bijective block swizzle: consecutive sorted blocks share dst rows ->
// keep them on the same XCD so the dst slice lives in that XCD's L2.
// ---------------------------------------------------------------------------
__global__ __launch_bounds__(256)
void k_edge(const uint4* __restrict__ qrows,
            const float* __restrict__ scales,
            const int* __restrict__ se_src,
            const int* __restrict__ se_dst,
            float* __restrict__ ew,
            float* __restrict__ deg, int ne, int nwg) {
    // bijective XCD swizzle (m204): hw -> logical
    int hw  = (int)blockIdx.x;
    int q   = nwg >> 3, r = nwg & 7;
    int xcd = hw & 7, idx = hw >> 3;
    int base = (xcd < r) ? xcd * (q + 1) : r * (q + 1) + (xcd - r) * q;
    int blk  = base + idx;

    int e  = blk * 32 + (int)(threadIdx.x >> 3);
    int gl = threadIdx.x & 7;
    if (e >= ne) return;
    int si = se_src[e], di = se_dst[e];
    const uint4* rs = qrows + (size_t)si * 32;
    const uint4* rd = qrows + (size_t)di * 32;
    uint4 a0 = rs[gl], a1 = rs[gl+8], a2 = rs[gl+16], a3 = rs[gl+24];
    uint4 b0 = rd[gl], b1 = rd[gl+8], b2 = rd[gl+16], b3 = rd[gl+24];
    int acc = dot4i8(a0.x,b0.x) + dot4i8(a0.y,b0.y) + dot4i8(a0.z,b0.z) + dot4i8(a0.w,b0.w)
            + dot4i8(a1.x,b1.x) + dot4i8(a1.y,b1.y) + dot4i8(a1.z,b1.z) + dot4i8(a1.w,b1.w)
            + dot4i8(a2.x,b2.x) + dot4i8(a2.y,b2.y) + dot4i8(a2.z,b2.z) + dot4i8(a2.w,b2.w)
            + dot4i8(a3.x,b3.x) + dot4i8(a3.y,b3.y) + dot4i8(a3.z,b3.z) + dot4i8(a3.w,b3.w);
    acc += __shfl_xor(acc, 4);
    acc += __shfl_xor(acc, 2);
    acc += __shfl_xor(acc, 1);
    if (gl == 0) {
        float w = (float)acc * scales[si] * scales[di];
        ew[e] = w;
        atomicAdd(&deg[di], w);
    }
}

// ---------------------------------------------------------------------------
// K_D (k_finish): t<ne : out[dst] += ew*rsqrt((deg_s+1)(deg_d+1))*sarr[src]
//                 t>=ne: out[i]   += sarr[i]/(deg[i]+1)
// ---------------------------------------------------------------------------
__global__ void k_finish(const int* __restrict__ se_src,
                         const int* __restrict__ se_dst,
                         const float* __restrict__ ew,
                         const float* __restrict__ deg,
                         const float* __restrict__ sarr,
                         float* __restrict__ out, int ne, int n) {
    int t = blockIdx.x * blockDim.x + threadIdx.x;
    if (t < ne) {
        int si = se_src[t], di = se_dst[t];
        float w = ew[t] * rsqrtf((deg[si] + 1.f) * (deg[di] + 1.f)) * sarr[si];
        atomicAdd(&out[di], w);
    } else if (t < ne + n) {
        int i = t - ne;
        atomicAdd(&out[i], sarr[i] / (deg[i] + 1.f));
    }
}

// ---------------------------------------------------------------------------
extern "C" void kernel_launch(void* const* d_in, const int* in_sizes, int n_in,
                              void* d_out, int out_size, void* d_ws, size_t ws_size,
                              hipStream_t stream) {
    const float* x     = (const float*)d_in[0];
    const int*   ei    = (const int*)  d_in[1];
    const float* face  = (const float*)d_in[2];
    const float* W1    = (const float*)d_in[3];
    const float* b1    = (const float*)d_in[4];
    const float* gamma = (const float*)d_in[5];
    const float* beta  = (const float*)d_in[6];
    const float* alpha = (const float*)d_in[7];
    const float* W2    = (const float*)d_in[8];
    const float* b2    = (const float*)d_in[9];
    const float* w0    = (const float*)d_in[10];
    const float* b0    = (const float*)d_in[11];
    const float* Wg    = (const float*)d_in[12];
    const float* bg    = (const float*)d_in[13];
    const float* wf    = (const float*)d_in[14];
    const float* bf    = (const float*)d_in[15];

    const int n  = in_sizes[0] / 2;   // 50000 nodes
    const int ne = in_sizes[1] / 2;   // 160000 edges
    const int* src = ei;
    const int* dst = ei + ne;
    const int nbkt = (n + 63) >> 6;   // 782 for n=50000 (<= MAXBKT)

    // workspace layout
    float* ws     = (float*)d_ws;
    uint2* qrows  = (uint2*)ws;                        // n*128 floats
    float* after  = ws + (size_t)n * 128;
    float* deg    = after;                             // [n]
    float* scales = after + n;                         // [n]
    float* sarr   = after + 2*(size_t)n;               // [n]
    float* ew     = after + 3*(size_t)n;               // [ne]
    int*   se_src = (int*)(after + 3*(size_t)n + ne);  // [ne]
    int*   se_dst = se_src + ne;                       // [ne]
    float* zreg   = (float*)(se_dst + ne);             // zeroed region:
    float* xs     = zreg;                              //   [8]
    int*   tick   = (int*)(zreg + 8);                  //   [2]
    int*   hist   = tick + 2;                          //   [MAXBKT]
    int*   bktptr = hist + MAXBKT;                     // [MAXBKT] (no zero)
    float* params = (float*)(bktptr + MAXBKT);         // [104]
    float* out    = (float*)d_out;

    const int qb  = (n + 3) / 4;          // quant blocks
    const int nbn = (n + 255) / 256;      // node blocks
    const int scb = (ne + 255) / 256;     // sort-scatter blocks
    const int ebk = (ne + 31) / 32;       // edge blocks (32 edges/block)

    hipMemsetAsync(zreg, 0, (10 + MAXBKT) * sizeof(int), stream);

    k_prep<<<qb + NB_XS + NBH, 256, 0, stream>>>(
        face, x, dst, qrows, scales, deg, xs, tick, hist, bktptr,
        W1, b1, gamma, beta, Wg, bg, wf, b0, bf, params, n, ne, qb, nbkt);

    k_mid<<<nbn + scb, 256, 0, stream>>>(
        x, W1, b1, alpha, W2, b2, w0, params, src, dst, bktptr,
        se_src, se_dst, sarr, out, n, ne, nbn);

    k_edge<<<ebk, 256, 0, stream>>>((const uint4*)qrows, scales,
                                    se_src, se_dst, ew, deg, ne, ebk);

    k_finish<<<(ne + n + 255) / 256, 256, 0, stream>>>(se_src, se_dst, ew,
                                                       deg, sarr, out, ne, n);
}

// Round 6
// 65.522 us; speedup vs baseline: 2.1470x; 2.1470x over previous
//
#include <hip/hip_runtime.h>

#define EPS_BN 1e-5f
#define FDIM 512        // face feature dim
#define F4   128        // FDIM/4
#define HDIM 32
#define NB_XS 64        // partial-sum blocks for xsums

// ---------------------------------------------------------------------------
__device__ __forceinline__ int dot4i8(unsigned a, unsigned b) {
#if __has_builtin(__builtin_amdgcn_sdot4)
    return __builtin_amdgcn_sdot4((int)a, (int)b, 0, false);
#else
    int s;
    s  = (int)(signed char)(a      ) * (int)(signed char)(b      );
    s += (int)(signed char)(a >>  8) * (int)(signed char)(b >>  8);
    s += (int)(signed char)(a >> 16) * (int)(signed char)(b >> 16);
    s += (int)(signed char)(a >> 24) * (int)(signed char)(b >> 24);
    return s;
#endif
}

// ---------------------------------------------------------------------------
// K_A (k_prep): blocks [0,qb): per-row normalize + int8 quantize (+zero deg)
//               blocks [qb,qb+NB_XS): 5-scalar sums over x -> atomicAdd xs[5]
// ---------------------------------------------------------------------------
__global__ __launch_bounds__(256)
void k_prep(const float* __restrict__ face,
            const float* __restrict__ x,
            uint2* __restrict__ qrows,   // [n*64] : 512 B/row
            float* __restrict__ scales,  // [n]
            float* __restrict__ deg,     // [n] zeroed here
            float* __restrict__ xs,      // [5] pre-zeroed
            int n, int qb) {
    int tid = threadIdx.x;
    if ((int)blockIdx.x < qb) {
        // ---- quant: one wave per row ----
        int row  = (int)((blockIdx.x * 256 + tid) >> 6);
        int lane = tid & 63;
        if (row >= n) return;
        const float4* f4 = (const float4*)face + (size_t)row * F4;
        float4 a = f4[lane];
        float4 b = f4[lane + 64];
        float ss = a.x*a.x + a.y*a.y + a.z*a.z + a.w*a.w
                 + b.x*b.x + b.y*b.y + b.z*b.z + b.w*b.w;
        float mx = fmaxf(fmaxf(fmaxf(fabsf(a.x), fabsf(a.y)),
                               fmaxf(fabsf(a.z), fabsf(a.w))),
                         fmaxf(fmaxf(fabsf(b.x), fabsf(b.y)),
                               fmaxf(fabsf(b.z), fabsf(b.w))));
        #pragma unroll
        for (int off = 32; off > 0; off >>= 1) {
            ss += __shfl_xor(ss, off);
            mx  = fmaxf(mx, __shfl_xor(mx, off));
        }
        float rn = rsqrtf(ss + 1e-12f);
        float qs = (mx > 0.f) ? 127.0f / mx : 0.f;
        unsigned da =  ((unsigned)(__float2int_rn(a.x*qs) & 255))
                    | (((unsigned)(__float2int_rn(a.y*qs) & 255)) << 8)
                    | (((unsigned)(__float2int_rn(a.z*qs) & 255)) << 16)
                    | (((unsigned)(__float2int_rn(a.w*qs) & 255)) << 24);
        unsigned db =  ((unsigned)(__float2int_rn(b.x*qs) & 255))
                    | (((unsigned)(__float2int_rn(b.y*qs) & 255)) << 8)
                    | (((unsigned)(__float2int_rn(b.z*qs) & 255)) << 16)
                    | (((unsigned)(__float2int_rn(b.w*qs) & 255)) << 24);
        qrows[(size_t)row * 64 + lane] = make_uint2(da, db);
        if (lane == 0) {
            scales[row] = mx * rn * (1.0f / 127.0f);
            deg[row]    = 0.f;
        }
    } else {
        // ---- xsums ----
        __shared__ float red[4][5];
        int bid = (int)blockIdx.x - qb;
        float s0=0.f, s1=0.f, s00=0.f, s01=0.f, s11=0.f;
        for (int i = bid * 256 + tid; i < n; i += NB_XS * 256) {
            float2 xv = ((const float2*)x)[i];
            s0  += xv.x;       s1  += xv.y;
            s00 += xv.x*xv.x;  s01 += xv.x*xv.y;  s11 += xv.y*xv.y;
        }
        #pragma unroll
        for (int off = 32; off > 0; off >>= 1) {
            s0  += __shfl_xor(s0,  off);
            s1  += __shfl_xor(s1,  off);
            s00 += __shfl_xor(s00, off);
            s01 += __shfl_xor(s01, off);
            s11 += __shfl_xor(s11, off);
        }
        int lane = tid & 63, w = tid >> 6;
        if (lane == 0) {
            red[w][0]=s0; red[w][1]=s1; red[w][2]=s00; red[w][3]=s01; red[w][4]=s11;
        }
        __syncthreads();
        if (tid < 5) {
            atomicAdd(&xs[tid],
                      red[0][tid] + red[1][tid] + red[2][tid] + red[3][tid]);
        }
    }
}

// ---------------------------------------------------------------------------
// K_B (k_main):
//   blocks [0,nbn): node — per-block recompute of fused params from xs
//                   (redundant but trivial), then encoder + sarr + out base
//   blocks [nbn,..): edge — 8 lanes/edge, 8x16B loads in flight per lane
// ---------------------------------------------------------------------------
__global__ __launch_bounds__(256)
void k_main(const float* __restrict__ x,
            const float* __restrict__ W1, const float* __restrict__ b1,
            const float* __restrict__ gamma, const float* __restrict__ beta,
            const float* __restrict__ alpha,
            const float* __restrict__ W2, const float* __restrict__ b2,
            const float* __restrict__ w0,
            const float* __restrict__ Wg, const float* __restrict__ bg,
            const float* __restrict__ wf,
            const float* __restrict__ b0, const float* __restrict__ bf,
            const float* __restrict__ xs,
            const uint4* __restrict__ qrows,
            const float* __restrict__ scales,
            const int* __restrict__ src, const int* __restrict__ dst,
            float* __restrict__ ew,
            float* __restrict__ deg,
            float* __restrict__ sarr,
            float* __restrict__ out,
            int n, int ne, int nbn) {
    if ((int)blockIdx.x < nbn) {
        // ---- node path ----
        __shared__ float sW2[HDIM*HDIM];
        __shared__ float sW1[2*HDIM], sb1[HDIM], sa[HDIM], sbsh[HDIM];
        __shared__ float sv[HDIM], sw0[HDIM], sb2[HDIM];
        __shared__ float sc, salpha;
        int tid = threadIdx.x;
        for (int i = tid; i < HDIM*HDIM; i += blockDim.x) sW2[i] = W2[i];
        if (tid < 2*HDIM) sW1[tid] = W1[tid];
        // per-block fused-params recompute (reads xs written by k_prep)
        if (tid < HDIM) {
            float invN = 1.0f / (float)n;
            float m0 = xs[0]*invN, m1 = xs[1]*invN;
            float c00 = xs[2]*invN - m0*m0;
            float c01 = xs[3]*invN - m0*m1;
            float c11 = xs[4]*invN - m1*m1;
            float w0j = W1[tid], w1j = W1[HDIM + tid];
            float mu  = m0*w0j + m1*w1j + b1[tid];
            float var = c00*w0j*w0j + 2.f*c01*w0j*w1j + c11*w1j*w1j;
            float aa  = gamma[tid] * rsqrtf(var + EPS_BN);
            sa[tid]   = aa;
            sbsh[tid] = beta[tid] - mu*aa;
            float v = 0.f;
            for (int m = 0; m < HDIM; ++m) v += Wg[tid*HDIM + m] * wf[m];
            sv[tid]  = v;
            sb1[tid] = b1[tid];
            sw0[tid] = w0[tid];
            sb2[tid] = b2[tid];
        } else if (tid == HDIM) {
            float c = b0[0] + bf[0];
            for (int m = 0; m < HDIM; ++m) c += bg[m] * wf[m];
            sc = c;
            salpha = alpha[0];
        }
        __syncthreads();
        int i = blockIdx.x * blockDim.x + tid;
        if (i >= n) return;
        float2 xv = ((const float2*)x)[i];
        float h[HDIM];
        #pragma unroll
        for (int j = 0; j < HDIM; ++j) {
            float t = xv.x*sW1[j] + xv.y*sW1[HDIM + j] + sb1[j];
            t = sa[j]*t + sbsh[j];
            h[j] = (t >= 0.f) ? t : salpha*t;
        }
        float em[HDIM];
        #pragma unroll
        for (int k = 0; k < HDIM; ++k) em[k] = sb2[k];
        #pragma unroll
        for (int j = 0; j < HDIM; ++j) {
            float hj = h[j];
            #pragma unroll
            for (int k = 0; k < HDIM; ++k) em[k] += hj * sW2[j*HDIM + k];
        }
        float sdot = 0.f, ldot = 0.f;
        #pragma unroll
        for (int k = 0; k < HDIM; ++k) { sdot += em[k]*sv[k]; ldot += em[k]*sw0[k]; }
        sarr[i] = sdot;
        out[i]  = ldot + sc;   // base; GCN terms added in k_finish
    } else {
        // ---- edge path: 8 lanes/edge, 32 edges/block ----
        int e  = ((int)blockIdx.x - nbn) * 32 + (int)(threadIdx.x >> 3);
        int gl = threadIdx.x & 7;
        if (e >= ne) return;
        int si = src[e], di = dst[e];
        const uint4* rs = qrows + (size_t)si * 32;
        const uint4* rd = qrows + (size_t)di * 32;
        uint4 a0 = rs[gl], a1 = rs[gl+8], a2 = rs[gl+16], a3 = rs[gl+24];
        uint4 b0 = rd[gl], b1 = rd[gl+8], b2 = rd[gl+16], b3 = rd[gl+24];
        int acc = dot4i8(a0.x,b0.x) + dot4i8(a0.y,b0.y) + dot4i8(a0.z,b0.z) + dot4i8(a0.w,b0.w)
                + dot4i8(a1.x,b1.x) + dot4i8(a1.y,b1.y) + dot4i8(a1.z,b1.z) + dot4i8(a1.w,b1.w)
                + dot4i8(a2.x,b2.x) + dot4i8(a2.y,b2.y) + dot4i8(a2.z,b2.z) + dot4i8(a2.w,b2.w)
                + dot4i8(a3.x,b3.x) + dot4i8(a3.y,b3.y) + dot4i8(a3.z,b3.z) + dot4i8(a3.w,b3.w);
        acc += __shfl_xor(acc, 4);
        acc += __shfl_xor(acc, 2);
        acc += __shfl_xor(acc, 1);
        if (gl == 0) {
            float w = (float)acc * scales[si] * scales[di];
            ew[e] = w;
            atomicAdd(&deg[di], w);
        }
    }
}

// ---------------------------------------------------------------------------
// K_C (k_finish): t<ne : out[dst] += ew*rsqrt((deg_s+1)(deg_d+1))*sarr[src]
//                 t>=ne: out[i]   += sarr[i]/(deg[i]+1)   (self loop)
// ---------------------------------------------------------------------------
__global__ void k_finish(const int* __restrict__ src,
                         const int* __restrict__ dst,
                         const float* __restrict__ ew,
                         const float* __restrict__ deg,
                         const float* __restrict__ sarr,
                         float* __restrict__ out, int ne, int n) {
    int t = blockIdx.x * blockDim.x + threadIdx.x;
    if (t < ne) {
        int si = src[t], di = dst[t];
        float w = ew[t] * rsqrtf((deg[si] + 1.f) * (deg[di] + 1.f)) * sarr[si];
        atomicAdd(&out[di], w);
    } else if (t < ne + n) {
        int i = t - ne;
        atomicAdd(&out[i], sarr[i] / (deg[i] + 1.f));
    }
}

// ---------------------------------------------------------------------------
extern "C" void kernel_launch(void* const* d_in, const int* in_sizes, int n_in,
                              void* d_out, int out_size, void* d_ws, size_t ws_size,
                              hipStream_t stream) {
    const float* x     = (const float*)d_in[0];
    const int*   ei    = (const int*)  d_in[1];
    const float* face  = (const float*)d_in[2];
    const float* W1    = (const float*)d_in[3];
    const float* b1    = (const float*)d_in[4];
    const float* gamma = (const float*)d_in[5];
    const float* beta  = (const float*)d_in[6];
    const float* alpha = (const float*)d_in[7];
    const float* W2    = (const float*)d_in[8];
    const float* b2    = (const float*)d_in[9];
    const float* w0    = (const float*)d_in[10];
    const float* b0    = (const float*)d_in[11];
    const float* Wg    = (const float*)d_in[12];
    const float* bg    = (const float*)d_in[13];
    const float* wf    = (const float*)d_in[14];
    const float* bf    = (const float*)d_in[15];

    const int n  = in_sizes[0] / 2;   // 50000 nodes
    const int ne = in_sizes[1] / 2;   // 160000 edges
    const int* src = ei;
    const int* dst = ei + ne;

    // workspace layout (floats). qrows first for 16B alignment.
    float* ws     = (float*)d_ws;
    uint2* qrows  = (uint2*)ws;                       // n*128 floats
    float* after  = ws + (size_t)n * 128;
    float* deg    = after;                            // [n]
    float* scales = after + n;                        // [n]
    float* sarr   = after + 2*(size_t)n;              // [n]
    float* ew     = after + 3*(size_t)n;              // [ne]
    float* xs     = after + 3*(size_t)n + ne;         // [8] (5 used)
    float* out    = (float*)d_out;

    const int qb  = (n + 3) / 4;          // quant blocks (4 rows/block)
    const int nbn = (n + 255) / 256;      // node blocks
    const int ebk = (ne + 31) / 32;       // edge blocks (32 edges/block)

    hipMemsetAsync(xs, 0, 8 * sizeof(float), stream);

    k_prep<<<qb + NB_XS, 256, 0, stream>>>(face, x, qrows, scales, deg, xs,
                                           n, qb);

    k_main<<<nbn + ebk, 256, 0, stream>>>(x, W1, b1, gamma, beta, alpha,
                                          W2, b2, w0, Wg, bg, wf, b0, bf, xs,
                                          (const uint4*)qrows, scales,
                                          src, dst, ew, deg, sarr, out,
                                          n, ne, nbn);

    k_finish<<<(ne + n + 255) / 256, 256, 0, stream>>>(src, dst, ew, deg,
                                                       sarr, out, ne, n);
}